// Round 11
// baseline (158.860 us; speedup 1.0000x reference)
//
#include <hip/hip_runtime.h>
#include <hip/hip_bf16.h>

#define BB 4
#define SS 32
#define HH 8
#define LL 128
#define DD 512
#define DI 2048
#define EPSN 1e-6f
#define INV_TEMP 0.04419417382415922f   // 1/sqrt(512)

#define NLOGIT_BLK 4096                  // B*S*L / 4 waves
#define NCAST_GRAN ((DI*DD/4)*2 + (DD*DD/4))   // 589824 float4 granules
#define NCAST_BLK (NCAST_GRAN / 256)     // 2304

#define NROW (BB*SS*HH)                  // 1024 rows
#define SLICE ((size_t)NROW * DD)        // floats per K-split partial

typedef __attribute__((ext_vector_type(8))) short short8;
typedef __attribute__((ext_vector_type(4))) float float4v;

static __device__ __forceinline__ unsigned short f2b(float f) {
  __hip_bfloat16 h = __float2bfloat16(f);
  return *(unsigned short*)&h;
}

// Fragment-packed layout (see r10): element (m,k) of an (M x K) operand at
//   ((((m>>4)*(K/32) + (k>>5))*4 + ((k>>3)&3))*16 + (m&15))*8 + (k&7)
// -> one MFMA fragment = one contiguous 1 KB wave read.
static __device__ __forceinline__ size_t pk(int m, int k, int K) {
  return ((((size_t)(m >> 4) * (K >> 5) + (k >> 5)) * 4 + ((k >> 3) & 3)) * 16
          + (m & 15)) * 8 + (k & 7);
}

// ---------------------------------------------------------------------------
// K1: fused [logits] + [weight cast -> fragment-packed bf16].  (r10 kernel)
// ---------------------------------------------------------------------------
__global__ __launch_bounds__(256) void pre_kernel(
    const float* __restrict__ x, const int* __restrict__ mask,
    const float* __restrict__ w, const float* __restrict__ w1,
    const float* __restrict__ w2, const float* __restrict__ v_w,
    unsigned short* __restrict__ w1b, unsigned short* __restrict__ w2b,
    unsigned short* __restrict__ v_wb, float* __restrict__ logits) {
  int blk = blockIdx.x;
  if (blk < NLOGIT_BLK) {
    int wv = threadIdx.x >> 6, lane = threadIdx.x & 63;
    int p  = blk * 4 + wv;
    int bs = p >> 7, l = p & (LL - 1);

    const float4* xr = (const float4*)(x + ((size_t)bs * LL + l) * DD) + lane * 2;
    float4 x0 = xr[0], x1 = xr[1];

    float acc[HH];
#pragma unroll
    for (int h = 0; h < HH; ++h) {
      const float4* wr = (const float4*)(w + ((size_t)h * LL + l) * DD) + lane * 2;
      float4 w0 = wr[0], w1v = wr[1];
      acc[h] = x0.x * w0.x + x0.y * w0.y + x0.z * w0.z + x0.w * w0.w +
               x1.x * w1v.x + x1.y * w1v.y + x1.z * w1v.z + x1.w * w1v.w;
    }
#pragma unroll
    for (int off = 32; off > 0; off >>= 1) {
#pragma unroll
      for (int h = 0; h < HH; ++h) acc[h] += __shfl_xor(acc[h], off);
    }
    if (lane == 0) {
      int msk = mask[bs * LL + l];
#pragma unroll
      for (int h = 0; h < HH; ++h) {
        float lg = msk ? acc[h] * INV_TEMP : -1e9f;
        logits[((size_t)bs * HH + h) * LL + l] = lg;
      }
    }
  } else {
    const int n1 = (DI * DD) / 4;    // w1 granules (N=2048,K=512)
    const int n2 = n1;               // w2 granules (N=512, K=2048)
    int i = (blk - NLOGIT_BLK) * 256 + threadIdx.x;
    float4 v;
    unsigned short* dst;
    size_t base;
    if (i < n1) {
      v = ((const float4*)w1)[i];
      dst = w1b;
      base = pk(i >> 7, (i & 127) * 4, DD);
    } else if (i < n1 + n2) {
      int j = i - n1;
      v = ((const float4*)w2)[j];
      dst = w2b;
      base = pk(j >> 9, (j & 511) * 4, DI);
    } else {
      int j = i - n1 - n2;
      v = ((const float4*)v_w)[j];
      dst = v_wb;
      base = pk(j >> 7, (j & 127) * 4, DD);
    }
    dst[base + 0] = f2b(v.x);
    dst[base + 1] = f2b(v.y);
    dst[base + 2] = f2b(v.z);
    dst[base + 3] = f2b(v.w);
  }
}

// ---------------------------------------------------------------------------
// K2: xa_v — softmax + xa (into LDS, fragment-packed) + v-projection MFMA
// for this block's 256-element K-chunk.  Block = (bs, half): grid 256, 512 thr.
// Writes vpart[half] (K-split x2 partials of out = xa @ v_w^T).
// ---------------------------------------------------------------------------
__global__ __launch_bounds__(512) void xa_v_kernel(
    const float* __restrict__ x, const float* __restrict__ logits,
    const unsigned short* __restrict__ v_wb, float* __restrict__ attn_out,
    float* __restrict__ vpart) {
  int bs = blockIdx.x >> 1, half = blockIdx.x & 1;
  int t = threadIdx.x, wv = t >> 6, lane = t & 63;
  int lm = lane & 15, lq = lane >> 4;

  __shared__ float sattn_t[LL][HH];            // 4 KB
  __shared__ float sxa[2][HH][256];            // 16 KB
  __shared__ unsigned short sxap[2048];        // packed xa chunk, 4 KB

  // softmax (waves 0-3)
  if (wv < 4) {
    for (int h = wv; h < HH; h += 4) {
      const float* lg = logits + ((size_t)bs * HH + h) * LL;
      float v0 = lg[lane], v1 = lg[lane + 64];
      float m = fmaxf(v0, v1);
#pragma unroll
      for (int off = 32; off > 0; off >>= 1) m = fmaxf(m, __shfl_xor(m, off));
      float e0 = __expf(v0 - m), e1 = __expf(v1 - m);
      float s = e0 + e1;
#pragma unroll
      for (int off = 32; off > 0; off >>= 1) s += __shfl_xor(s, off);
      float inv = 1.f / s;
      e0 *= inv; e1 *= inv;
      sattn_t[lane][h]      = e0;
      sattn_t[lane + 64][h] = e1;
      if (half == 0) {
        float* ao = attn_out + ((size_t)bs * HH + h) * LL;
        ao[lane]      = e0;
        ao[lane + 64] = e1;
      }
    }
  }
  __syncthreads();

  // xa for this half's 256 columns; l-range split over two thread-groups
  int col = t & 255, lseg = t >> 8;
  int e = half * 256 + col;
  const float* xb = x + (size_t)bs * LL * DD;
  {
    float acc[HH];
#pragma unroll
    for (int h = 0; h < HH; ++h) acc[h] = 0.f;
    int l0 = lseg * 64;
    for (int l = l0; l < l0 + 64; ++l) {
      float xv = xb[(size_t)l * DD + e];
      float4 a0 = *(const float4*)&sattn_t[l][0];
      float4 a1 = *(const float4*)&sattn_t[l][4];
      acc[0] += a0.x * xv; acc[1] += a0.y * xv;
      acc[2] += a0.z * xv; acc[3] += a0.w * xv;
      acc[4] += a1.x * xv; acc[5] += a1.y * xv;
      acc[6] += a1.z * xv; acc[7] += a1.w * xv;
    }
#pragma unroll
    for (int h = 0; h < HH; ++h) sxa[lseg][h][col] = acc[h];
  }
  __syncthreads();
  if (t < 256) {
    int c = t >> 5, q = (t >> 3) & 3, el = t & 7;   // local k = t
#pragma unroll
    for (int h = 0; h < HH; ++h)
      sxap[(((c * 4 + q) * 8) + h) * 8 + el] = f2b(sxa[0][h][t] + sxa[1][h][t]);
  }
  __syncthreads();

  // v-projection partial: A = 8 xa rows (dup to 16) x 256 K, B = v_wb chunk.
  // wave wv owns cols wv*64..+63 (4 n-frags).
  {
    const short8* B8 = (const short8*)v_wb;
    float4v acc[4];
#pragma unroll
    for (int nf = 0; nf < 4; ++nf) acc[nf] = (float4v){0.f, 0.f, 0.f, 0.f};
#pragma unroll
    for (int c = 0; c < 8; ++c) {
      short8 a = *(const short8*)&sxap[(((c * 4 + lq) * 8) + (lm & 7)) * 8];
#pragma unroll
      for (int nf = 0; nf < 4; ++nf) {
        int np = wv * 4 + nf;
        short8 b = B8[((size_t)np * 16 + half * 8 + c) * 64 + lane];
        acc[nf] = __builtin_amdgcn_mfma_f32_16x16x32_bf16(a, b, acc[nf], 0, 0, 0);
      }
    }
    if (lq < 2) {
      float* outp = vpart + (size_t)half * SLICE;
#pragma unroll
      for (int nf = 0; nf < 4; ++nf) {
        int cc = wv * 64 + nf * 16 + lm;
#pragma unroll
        for (int r = 0; r < 4; ++r) {
          int m = bs * HH + lq * 4 + r;
          outp[(size_t)m * DD + cc] = acc[nf][r];
        }
      }
    }
  }
}

// ---------------------------------------------------------------------------
// K3: g1 — fused mid-LN + GEMM1 + ReLU.  Block = (mt,nt): grid 512, 256 thr.
// Phase 1: sum 2 vpart slices for the 64-row panel, LN, pack bf16 into LDS
//          (nt==0 blocks also write o_ln fp32 for the residual).
// Phase 2: h1 = relu(A @ w1^T + b1) -> h1b fragment-packed.
// ---------------------------------------------------------------------------
__global__ __launch_bounds__(256) void g1_kernel(
    const float* __restrict__ vpart, const float* __restrict__ ln_g,
    const float* __restrict__ ln_b, const unsigned short* __restrict__ w1b,
    const float* __restrict__ b1, float* __restrict__ o_ln,
    unsigned short* __restrict__ h1b) {
  int blk = blockIdx.x;
  int nt = blk & 31, mt = blk >> 5;
  int wv = threadIdx.x >> 6, lane = threadIdx.x & 63;
  int lm = lane & 15, lq = lane >> 4;

  __shared__ unsigned short sA[64 * 512];   // packed A panel, 64 KB

  // Phase 1: LN of 16 rows per wave
  {
    const float* gg = ln_g + lane * 8;
    const float* gb = ln_b + lane * 8;
    float g0 = gg[0], g1v = gg[1], g2 = gg[2], g3 = gg[3];
    float g4 = gg[4], g5 = gg[5], g6 = gg[6], g7 = gg[7];
    float bb0 = gb[0], bb1 = gb[1], bb2 = gb[2], bb3 = gb[3];
    float bb4 = gb[4], bb5 = gb[5], bb6 = gb[6], bb7 = gb[7];
    for (int i = 0; i < 16; ++i) {
      int row = mt * 64 + wv * 16 + i;
      const float* p0 = vpart + (size_t)row * DD + lane * 8;
      float4 a0 = *(const float4*)p0;
      float4 a1 = *(const float4*)(p0 + 4);
      float4 c0 = *(const float4*)(p0 + SLICE);
      float4 c1 = *(const float4*)(p0 + SLICE + 4);
      float v0 = a0.x + c0.x, v1 = a0.y + c0.y, v2 = a0.z + c0.z, v3 = a0.w + c0.w;
      float v4 = a1.x + c1.x, v5 = a1.y + c1.y, v6 = a1.z + c1.z, v7 = a1.w + c1.w;
      float sum = v0 + v1 + v2 + v3 + v4 + v5 + v6 + v7;
      float sq  = v0*v0 + v1*v1 + v2*v2 + v3*v3 + v4*v4 + v5*v5 + v6*v6 + v7*v7;
#pragma unroll
      for (int off = 32; off > 0; off >>= 1) {
        sum += __shfl_xor(sum, off);
        sq  += __shfl_xor(sq, off);
      }
      float mu  = sum * (1.f / DD);
      float var = sq * (1.f / DD) - mu * mu;
      float rs  = rsqrtf(var + EPSN);
      float y0 = (v0 - mu) * rs * g0 + bb0, y1 = (v1 - mu) * rs * g1v + bb1;
      float y2 = (v2 - mu) * rs * g2 + bb2, y3 = (v3 - mu) * rs * g3 + bb3;
      float y4 = (v4 - mu) * rs * g4 + bb4, y5 = (v5 - mu) * rs * g5 + bb5;
      float y6 = (v6 - mu) * rs * g6 + bb6, y7 = (v7 - mu) * rs * g7 + bb7;
      // LDS packed: panel wv, chunk c=lane>>2, quad q=lane&3, row-in-panel i
      unsigned short* d = &sA[((((wv * 16 + (lane >> 2)) * 4 + (lane & 3)) * 16) + i) * 8];
      d[0] = f2b(y0); d[1] = f2b(y1); d[2] = f2b(y2); d[3] = f2b(y3);
      d[4] = f2b(y4); d[5] = f2b(y5); d[6] = f2b(y6); d[7] = f2b(y7);
      if (nt == 0) {
        float* op = o_ln + (size_t)row * DD + lane * 8;
        *(float4*)op = (float4){y0, y1, y2, y3};
        *(float4*)(op + 4) = (float4){y4, y5, y6, y7};
      }
    }
  }
  __syncthreads();

  // Phase 2: gemm; wave wv = rows panel wv, cols nt*64..+63
  {
    const short8* B8 = (const short8*)w1b;
    float4v acc[4];
#pragma unroll
    for (int nf = 0; nf < 4; ++nf) acc[nf] = (float4v){0.f, 0.f, 0.f, 0.f};
#pragma unroll 4
    for (int c = 0; c < 16; ++c) {
      short8 a = *(const short8*)&sA[((((wv * 16 + c) * 4 + lq) * 16) + lm) * 8];
#pragma unroll
      for (int nf = 0; nf < 4; ++nf) {
        int np = nt * 4 + nf;
        short8 b = B8[((size_t)np * 16 + c) * 64 + lane];
        acc[nf] = __builtin_amdgcn_mfma_f32_16x16x32_bf16(a, b, acc[nf], 0, 0, 0);
      }
    }
#pragma unroll
    for (int nf = 0; nf < 4; ++nf) {
      int col = nt * 64 + nf * 16 + lm;
      float bb = b1[col];
#pragma unroll
      for (int r = 0; r < 4; ++r) {
        int row = mt * 64 + wv * 16 + lq * 4 + r;
        h1b[pk(row, col, DI)] = f2b(fmaxf(acc[nf][r] + bb, 0.f));
      }
    }
  }
}

// ---------------------------------------------------------------------------
// K4: GEMM2  ypart[ks] = h1 @ w2^T.  M=1024 N=512 K=2048, K-split x4. (r10)
// ---------------------------------------------------------------------------
__global__ __launch_bounds__(256) void gemm2_kernel(
    const unsigned short* __restrict__ h1b, const unsigned short* __restrict__ w2b,
    float* __restrict__ ypart) {
  int blk = blockIdx.x;
  int nt = blk & 7, mt = (blk >> 3) & 15, kslice = blk >> 7;
  int wv = threadIdx.x >> 6, lane = threadIdx.x & 63;
  int lm = lane & 15, lq = lane >> 4;

  int m0 = mt * 64 + wv * 16;
  int n0 = nt * 64;
  const short8* A8 = (const short8*)h1b + (size_t)(m0 >> 4) * 64 * 64;   // K/32=64
  const short8* B8 = (const short8*)w2b;

  float4v acc[4];
#pragma unroll
  for (int nf = 0; nf < 4; ++nf) acc[nf] = (float4v){0.f, 0.f, 0.f, 0.f};

#pragma unroll 4
  for (int ci = 0; ci < 16; ++ci) {
    int c = kslice * 16 + ci;
    short8 a = A8[(size_t)c * 64 + lane];
#pragma unroll
    for (int nf = 0; nf < 4; ++nf) {
      short8 b = B8[((size_t)((n0 >> 4) + nf) * 64 + c) * 64 + lane];
      acc[nf] = __builtin_amdgcn_mfma_f32_16x16x32_bf16(a, b, acc[nf], 0, 0, 0);
    }
  }

  float* outp = ypart + (size_t)kslice * SLICE;
#pragma unroll
  for (int nf = 0; nf < 4; ++nf) {
    int col = n0 + nf * 16 + lm;
#pragma unroll
    for (int r = 0; r < 4; ++r)
      outp[(size_t)(m0 + lq * 4 + r) * DD + col] = acc[nf][r];
  }
}

// ---------------------------------------------------------------------------
// K5: final LN:  y = LN(sum ypart + b2 + o_ln)*g + b.  (r10)
// ---------------------------------------------------------------------------
__global__ __launch_bounds__(256) void ln_final_kernel(
    const float* __restrict__ ypart, const float* __restrict__ o_ln,
    const float* __restrict__ b2, const float* __restrict__ fln_g,
    const float* __restrict__ fln_b, float* __restrict__ y_out) {
  int wv = threadIdx.x >> 6, lane = threadIdx.x & 63;
  int row = blockIdx.x * 4 + wv;

  const float* p0 = ypart + (size_t)row * DD;
  const float* ol = o_ln + (size_t)row * DD;
  float vals[8];
  float sum = 0.f, sq = 0.f;
#pragma unroll
  for (int k = 0; k < 8; ++k) {
    int d = lane + 64 * k;
    float v = p0[d] + p0[SLICE + d] + p0[2 * SLICE + d] + p0[3 * SLICE + d] +
              b2[d] + ol[d];
    vals[k] = v;
    sum += v;
    sq += v * v;
  }
#pragma unroll
  for (int off = 32; off > 0; off >>= 1) {
    sum += __shfl_xor(sum, off);
    sq  += __shfl_xor(sq, off);
  }
  float mu  = sum * (1.f / DD);
  float var = sq * (1.f / DD) - mu * mu;
  float rs  = rsqrtf(var + EPSN);
  float* yo = y_out + (size_t)row * DD;
#pragma unroll
  for (int k = 0; k < 8; ++k) {
    int d = lane + 64 * k;
    yo[d] = (vals[k] - mu) * rs * fln_g[d] + fln_b[d];
  }
}

extern "C" void kernel_launch(void* const* d_in, const int* in_sizes, int n_in,
                              void* d_out, int out_size, void* d_ws, size_t ws_size,
                              hipStream_t stream) {
  const float* x     = (const float*)d_in[0];
  const int*   mask  = (const int*)d_in[1];
  const float* w     = (const float*)d_in[2];
  const float* v_w   = (const float*)d_in[3];
  const float* ln_g  = (const float*)d_in[4];
  const float* ln_b  = (const float*)d_in[5];
  const float* w1    = (const float*)d_in[6];
  const float* b1    = (const float*)d_in[7];
  const float* w2    = (const float*)d_in[8];
  const float* b2    = (const float*)d_in[9];
  const float* fln_g = (const float*)d_in[10];
  const float* fln_b = (const float*)d_in[11];

  float* y    = (float*)d_out;
  float* attn = y + (size_t)BB * SS * HH * DD;

  // workspace layout (bytes)
  char* ws = (char*)d_ws;
  float*          o_ln   = (float*)(ws);                       // 2 MB
  unsigned short* w1b    = (unsigned short*)(ws + 2097152);    // 2 MB
  unsigned short* w2b    = (unsigned short*)(ws + 4194304);    // 2 MB
  unsigned short* h1b    = (unsigned short*)(ws + 6291456);    // 4 MB
  float*          ypart  = (float*)(ws + 10485760);            // 8 MB (4 slices)
  unsigned short* v_wb   = (unsigned short*)(ws + 18874368);   // 512 KB
  float*          vpart  = (float*)(ws + 19398656);            // 4 MB (2 slices)
  float*          logits = (float*)(ws + 23592960);            // 512 KB

  pre_kernel<<<NLOGIT_BLK + NCAST_BLK, 256, 0, stream>>>(
      x, mask, w, w1, w2, v_w, w1b, w2b, v_wb, logits);
  xa_v_kernel<<<BB * SS * 2, 512, 0, stream>>>(x, logits, v_wb, attn, vpart);
  g1_kernel<<<512, 256, 0, stream>>>(vpart, ln_g, ln_b, w1b, b1, o_ln, h1b);
  gemm2_kernel<<<512, 256, 0, stream>>>(h1b, w2b, ypart);
  ln_final_kernel<<<256, 256, 0, stream>>>(ypart, o_ln, b2, fln_g, fln_b, y);
}